// Round 7
// baseline (118.504 us; speedup 1.0000x reference)
//
#include <hip/hip_runtime.h>

#define SC 0.70710678118654752440f

typedef _Float16 h4v __attribute__((ext_vector_type(4)));

__device__ __forceinline__ float4 ld4(const float* __restrict__ p) {
    return *(const float4*)p;
}
__device__ __forceinline__ float4 ld4(const _Float16* __restrict__ p) {
    h4v h = *(const h4v*)p;
    return make_float4((float)h[0], (float)h[1], (float)h[2], (float)h[3]);
}
__device__ __forceinline__ void st4(float* __restrict__ p, float4 v) {
    *(float4*)p = v;
}
__device__ __forceinline__ void st4(_Float16* __restrict__ p, float4 v) {
    h4v h;
    h[0] = (_Float16)v.x; h[1] = (_Float16)v.y;
    h[2] = (_Float16)v.z; h[3] = (_Float16)v.w;
    *(h4v*)p = h;
}
__device__ __forceinline__ h4v f2h(float4 v) {
    h4v h;
    h[0] = (_Float16)v.x; h[1] = (_Float16)v.y;
    h[2] = (_Float16)v.z; h[3] = (_Float16)v.w;
    return h;
}
__device__ __forceinline__ float4 h2f(h4v h) {
    return make_float4((float)h[0], (float)h[1], (float)h[2], (float)h[3]);
}

// branchless half-sample reflection in [0, n)
__device__ __forceinline__ int reflFull(int p, int n) {
    int x = max(p, ~p);
    return min(x, 2 * n - 1 - x);
}

// pair-space reflection: NP pairs; reflected pair index + swap flag
__device__ __forceinline__ int pairRefl(int t, int NP, bool& sw) {
    int x = max(t, ~t);
    int tp = min(x, 2 * NP - 1 - x);
    sw = (tp != t);
    return tp;
}

// coefficient index maps: cfl[s][k] = g0b[cflIdx], cfh[s][k] = g1a[cfhIdx]
__device__ __forceinline__ constexpr int cflIdx(int s, int k) {
    return (s == 0) ? 8 - 2 * k : (s == 1) ? 1 + 2 * k : (s == 2) ? 9 - 2 * k : 2 * k;
}
__device__ __forceinline__ constexpr int cfhIdx(int s, int k) {
    return (s == 0) ? 1 + 2 * k : (s == 1) ? 8 - 2 * k : (s == 2) ? 2 * k : 9 - 2 * k;
}

__device__ __forceinline__ float4 f4fma(float c, float4 a, float4 acc) {
    return make_float4(fmaf(c, a.x, acc.x), fmaf(c, a.y, acc.y),
                       fmaf(c, a.z, acc.z), fmaf(c, a.w, acc.w));
}
__device__ __forceinline__ float4 f4sel(bool sw, float4 a, float4 b) {
    return sw ? a : b;
}

struct Band4 { float4 e05, o05, e23, o23, e14, o14; };

// load 6 band float4s (2 complex = 4 output cols) at pair-row offset; produce
// even/odd-row-slot c2q values (unscaled by SC); sw swaps even/odd slots
__device__ __forceinline__ Band4 loadBands4(const float* __restrict__ bp, int HW2,
                                            int boff, bool sw) {
    float4 B0 = *(const float4*)(bp + 0 * HW2 + boff);
    float4 B1 = *(const float4*)(bp + 1 * HW2 + boff);
    float4 B2 = *(const float4*)(bp + 2 * HW2 + boff);
    float4 B3 = *(const float4*)(bp + 3 * HW2 + boff);
    float4 B4 = *(const float4*)(bp + 4 * HW2 + boff);
    float4 B5 = *(const float4*)(bp + 5 * HW2 + boff);
    float4 ve05 = {B0.x + B5.x, B0.y + B5.y, B0.z + B5.z, B0.w + B5.w};
    float4 vo05 = {B0.y - B5.y, B5.x - B0.x, B0.w - B5.w, B5.z - B0.z};
    float4 ve23 = {B2.x + B3.x, B2.y + B3.y, B2.z + B3.z, B2.w + B3.w};
    float4 vo23 = {B2.y - B3.y, B3.x - B2.x, B2.w - B3.w, B3.z - B2.z};
    float4 ve14 = {B1.x + B4.x, B1.y + B4.y, B1.z + B4.z, B1.w + B4.w};
    float4 vo14 = {B1.y - B4.y, B4.x - B1.x, B1.w - B4.w, B4.z - B1.z};
    Band4 r;
    r.e05 = f4sel(sw, vo05, ve05);  r.o05 = f4sel(sw, ve05, vo05);
    r.e23 = f4sel(sw, vo23, ve23);  r.o23 = f4sel(sw, ve23, vo23);
    r.e14 = f4sel(sw, vo14, ve14);  r.o14 = f4sel(sw, ve14, vo14);
    return r;
}

template <int N> struct Log2 { static constexpr int v = 1 + Log2<N / 2>::v; };
template <> struct Log2<1> { static constexpr int v = 0; };

// ---------------------------------------------------------------------------
// Fused j2 level: ll (nc,2H,2W) + yh (nc,6,H,W,2) -> out (nc,4H,4W)
// Col stage: 256 packs (pk,u4), each = 8 rows (2 q) x 4 cols -> LDS fp16.
// Row stage: full-width, 8 cols (2 quads) per task.
// ---------------------------------------------------------------------------
template <int H, int W, typename TIn, typename TOut>
__global__ __launch_bounds__(256) void j2_fused(
        const TIn* __restrict__ ll, const float* __restrict__ yh,
        const float* __restrict__ g0b, const float* __restrict__ g1a,
        TOut* __restrict__ out) {
    constexpr int LOGW = Log2<W>::v;
    constexpr int U4 = W / 2, LOGU4 = LOGW - 1;
    constexpr int P = 256 / U4;          // packs of 8 rows
    constexpr int TI = 8 * P;            // tile rows
    constexpr int r = 2 * H, COUT = 4 * W, LOGC2 = LOGW + 1;
    constexpr int HW2 = H * W * 2;
    __shared__ h4v sY[TI][W];            // [row][pair] = {y1e,y1o,y2e,y2o} fp16

    const int tid = threadIdx.x;
    const int nc = blockIdx.y;
    const int q0 = blockIdx.x * (TI / 4);
    const TIn* llp = ll + (size_t)nc * r * (2 * W);
    const float* bp  = yh + (size_t)nc * 6 * HW2;

    float G0[10], G1[10], SG0[10], SG1[10];
#pragma unroll
    for (int i = 0; i < 10; ++i) {
        G0[i] = g0b[i]; G1[i] = g1a[i];
        SG0[i] = SC * G0[i]; SG1[i] = SC * G1[i];
    }

    // ---- col stage: 2 q (8 rows) x 4 cols per thread
    {
        int u4 = tid & (U4 - 1);
        int pk = tid >> LOGU4;
        int qp = q0 + 2 * pk;
        float4 A1[2][4], A2[2][4];
#pragma unroll
        for (int qa = 0; qa < 2; ++qa)
#pragma unroll
            for (int s = 0; s < 4; ++s) { A1[qa][s] = {0,0,0,0}; A2[qa][s] = {0,0,0,0}; }

#pragma unroll
        for (int tt = 0; tt < 6; ++tt) {
            int t = qp - 2 + tt;
            int pe = reflFull(2 * t, r);
            int po = reflFull(2 * t + 1, r);
            float4 lle = ld4(llp + ((pe << LOGC2) + 4 * u4));
            float4 llo = ld4(llp + ((po << LOGC2) + 4 * u4));
            bool sw; int tp = pairRefl(t, H, sw);
            Band4 B = loadBands4(bp, HW2, (tp << (LOGW + 1)) + 4 * u4, sw);
#pragma unroll
            for (int qa = 0; qa < 2; ++qa) {
                int k = tt - qa;
                if (k < 0 || k > 4) continue;
#pragma unroll
                for (int s = 0; s < 4; ++s) {
                    float4 lv  = (s & 1) ? llo   : lle;
                    float4 v05 = (s & 1) ? B.e05 : B.o05;
                    float4 v23 = (s & 1) ? B.o23 : B.e23;
                    float4 v14 = (s & 1) ? B.e14 : B.o14;
                    A1[qa][s] = f4fma(G0[cflIdx(s, k)], lv,
                                f4fma(SG1[cfhIdx(s, k)], v05, A1[qa][s]));
                    A2[qa][s] = f4fma(SG0[cflIdx(s, k)], v23,
                                f4fma(SG1[cfhIdx(s, k)], v14, A2[qa][s]));
                }
            }
        }
#pragma unroll
        for (int qa = 0; qa < 2; ++qa)
#pragma unroll
            for (int s = 0; s < 4; ++s) {
                int row = 8 * pk + 4 * qa + s;
                float4 w1 = A1[qa][s], w2 = A2[qa][s];
                sY[row][2 * u4]     = f2h(make_float4(w1.x, w1.y, w2.x, w2.y));
                sY[row][2 * u4 + 1] = f2h(make_float4(w1.z, w1.w, w2.z, w2.w));
            }
    }
    __syncthreads();

    // ---- row stage: 8 cols (2 quads) per task
    TOut* op = out + (size_t)nc * (4 * H) * COUT;
#pragma unroll
    for (int v = 0; v < (TI * W) / 512; ++v) {
        int lin = v * 256 + tid;
        int uc = lin & (U4 - 1);
        int il = lin >> LOGU4;
        float e1[6], o1[6], e2[6], o2[6];
#pragma unroll
        for (int m = 0; m < 6; ++m) {
            int t = 2 * uc - 2 + m;
            bool sw; int tp = pairRefl(t, W, sw);
            float4 F = h2f(sY[il][tp]);
            e1[m] = sw ? F.y : F.x;  o1[m] = sw ? F.x : F.y;
            e2[m] = sw ? F.w : F.z;  o2[m] = sw ? F.z : F.w;
        }
        float acc[8];
#pragma unroll
        for (int b = 0; b < 2; ++b)
#pragma unroll
            for (int s = 0; s < 4; ++s) {
                float a = 0.f;
#pragma unroll
                for (int k = 0; k < 5; ++k) {
                    int m = b + k;
                    float v1 = (s & 1) ? o1[m] : e1[m];
                    float v2 = (s & 1) ? e2[m] : o2[m];
                    a = fmaf(G0[cflIdx(s, k)], v1, a);
                    a = fmaf(G1[cfhIdx(s, k)], v2, a);
                }
                acc[4 * b + s] = a;
            }
        int grow = 4 * q0 + il;
        st4(op + (size_t)grow * COUT + 8 * uc,
            make_float4(acc[0], acc[1], acc[2], acc[3]));
        st4(op + (size_t)grow * COUT + 8 * uc + 4,
            make_float4(acc[4], acc[5], acc[6], acc[7]));
    }
}

// ---------------------------------------------------------------------------
// Fused j1: ll (nc,r,c) + yh (nc,6,H,W,2) -> out (nc,r,c), r=2H, c=2W
// Col stage: 2 qi (8 rows) x 4 cols per thread; row stage 8 cols per task.
// ---------------------------------------------------------------------------
template <int H, int W, typename TIn>
__global__ __launch_bounds__(256) void j1_fused(
        const TIn* __restrict__ ll, const float* __restrict__ yh,
        const float* __restrict__ g0o, const float* __restrict__ g1o,
        float* __restrict__ out) {
    constexpr int LOGW = Log2<W>::v;
    constexpr int U4 = W / 2, LOGU4 = LOGW - 1;
    constexpr int P = 256 / U4;          // packs (=4)
    constexpr int TI = 8 * P;            // tile rows (=32)
    constexpr int r = 2 * H, c = 2 * W, LOGC2 = LOGW + 1;
    constexpr int HW2 = H * W * 2;
    __shared__ h4v sY[TI][W];

    const int tid = threadIdx.x;
    const int nc = blockIdx.y;
    const int qi0 = blockIdx.x * (TI / 4);
    const TIn* llp = ll + (size_t)nc * r * c;
    const float* bp  = yh + (size_t)nc * 6 * HW2;

    float g0f[7], g1f[5], Sg0f[7], Sg1f[5];
#pragma unroll
    for (int k = 0; k < 7; ++k) { g0f[k] = g0o[6 - k]; Sg0f[k] = SC * g0f[k]; }
#pragma unroll
    for (int k = 0; k < 5; ++k) { g1f[k] = g1o[4 - k]; Sg1f[k] = SC * g1f[k]; }

    // ---- col stage
    {
        int u4 = tid & (U4 - 1);
        int pk = tid >> LOGU4;
        int qp = qi0 + 2 * pk;
        float4 A1[2][4], A2[2][4];
#pragma unroll
        for (int qa = 0; qa < 2; ++qa)
#pragma unroll
            for (int di = 0; di < 4; ++di) { A1[qa][di] = {0,0,0,0}; A2[qa][di] = {0,0,0,0}; }

        // ll contribution (g0, rows 4qp-3 .. 4qp+10)
#pragma unroll
        for (int rr = 0; rr < 14; ++rr) {
            int p = reflFull(4 * qp - 3 + rr, r);
            float4 v = ld4(llp + ((p << LOGC2) + 4 * u4));
#pragma unroll
            for (int qa = 0; qa < 2; ++qa)
#pragma unroll
                for (int di = 0; di < 4; ++di) {
                    int k = rr - 4 * qa - di;
                    if (k >= 0 && k <= 6) A1[qa][di] = f4fma(g0f[k], v, A1[qa][di]);
                }
        }
        // band contributions (pair rows 2qp-2 .. 2qp+5)
#pragma unroll
        for (int tt = 0; tt < 8; ++tt) {
            int t = 2 * qp - 2 + tt;
            bool sw; int tp = pairRefl(t, H, sw);
            Band4 B = loadBands4(bp, HW2, (tp << (LOGW + 1)) + 4 * u4, sw);
#pragma unroll
            for (int qa = 0; qa < 2; ++qa) {
                int tr = tt - 2 * qa;
                if (tr < 0 || tr > 5) continue;
#pragma unroll
                for (int di = 0; di < 4; ++di) {
                    int k1e = 2 * tr - di - 2;
                    int k1o = k1e + 1;
                    int k0e = 2 * tr - di - 1;
                    int k0o = k0e + 1;
                    if (k1e >= 0 && k1e <= 4) {
                        A1[qa][di] = f4fma(Sg1f[k1e], B.e05, A1[qa][di]);
                        A2[qa][di] = f4fma(Sg1f[k1e], B.e14, A2[qa][di]);
                    }
                    if (k1o >= 0 && k1o <= 4) {
                        A1[qa][di] = f4fma(Sg1f[k1o], B.o05, A1[qa][di]);
                        A2[qa][di] = f4fma(Sg1f[k1o], B.o14, A2[qa][di]);
                    }
                    if (k0e >= 0 && k0e <= 6) A2[qa][di] = f4fma(Sg0f[k0e], B.e23, A2[qa][di]);
                    if (k0o >= 0 && k0o <= 6) A2[qa][di] = f4fma(Sg0f[k0o], B.o23, A2[qa][di]);
                }
            }
        }
#pragma unroll
        for (int qa = 0; qa < 2; ++qa)
#pragma unroll
            for (int di = 0; di < 4; ++di) {
                int row = 8 * pk + 4 * qa + di;
                float4 w1 = A1[qa][di], w2 = A2[qa][di];
                sY[row][2 * u4]     = f2h(make_float4(w1.x, w1.y, w2.x, w2.y));
                sY[row][2 * u4 + 1] = f2h(make_float4(w1.z, w1.w, w2.z, w2.w));
            }
    }
    __syncthreads();

    // ---- row stage: 8 cols (2 quads) per task
    float* op = out + (size_t)nc * r * c;
#pragma unroll
    for (int v = 0; v < (TI * W) / 1024; ++v) {
        int lin = v * 256 + tid;
        int g8 = lin & (W / 4 - 1);     // 8-col group
        int il = lin >> (LOGW - 2);
        float e1[8], o1[8], e2[8], o2[8];
#pragma unroll
        for (int m = 0; m < 8; ++m) {
            int t = 4 * g8 - 2 + m;
            bool sw; int tp = pairRefl(t, W, sw);
            float4 F = h2f(sY[il][tp]);
            e1[m] = sw ? F.y : F.x;  o1[m] = sw ? F.x : F.y;
            e2[m] = sw ? F.w : F.z;  o2[m] = sw ? F.z : F.w;
        }
        float acc[8];
#pragma unroll
        for (int b = 0; b < 2; ++b)
#pragma unroll
            for (int s = 0; s < 4; ++s) {
                float a = 0.f;
#pragma unroll
                for (int k = 0; k < 7; ++k) {
                    int rel = s + k + 1;
                    int mm = (rel >> 1) + 2 * b;
                    a = fmaf(g0f[k], (rel & 1) ? o1[mm] : e1[mm], a);
                }
#pragma unroll
                for (int k = 0; k < 5; ++k) {
                    int rel = s + k + 2;
                    int mm = (rel >> 1) + 2 * b;
                    a = fmaf(g1f[k], (rel & 1) ? o2[mm] : e2[mm], a);
                }
                acc[4 * b + s] = a;
            }
        int grow = 4 * qi0 + il;
        *(float4*)(op + (size_t)grow * c + 8 * g8) =
            make_float4(acc[0], acc[1], acc[2], acc[3]);
        *(float4*)(op + (size_t)grow * c + 8 * g8 + 4) =
            make_float4(acc[4], acc[5], acc[6], acc[7]);
    }
}

extern "C" void kernel_launch(void* const* d_in, const int* in_sizes, int n_in,
                              void* d_out, int out_size, void* d_ws, size_t ws_size,
                              hipStream_t stream) {
    const float* yl  = (const float*)d_in[0];
    const float* yh1 = (const float*)d_in[1];
    const float* yh2 = (const float*)d_in[2];
    const float* yh3 = (const float*)d_in[3];
    const float* g0o = (const float*)d_in[4];
    const float* g1o = (const float*)d_in[5];
    const float* g0b = (const float*)d_in[7];
    const float* g1a = (const float*)d_in[8];
    float* out = (float*)d_out;

    const int NC = 256;
    char* ws = (char*)d_ws;
    _Float16* llA = (_Float16*)ws;                        // (NC,128,128) fp16, 8MB
    _Float16* llB = (_Float16*)(ws + ((size_t)16 << 20)); // (NC,256,256) fp16, 32MB

    // Level 3: yl (fp32) + yh3 -> llA (fp16). TI=128 -> grid.x = 1.
    j2_fused<32, 32, float, _Float16><<<dim3(1, NC), 256, 0, stream>>>(
        yl, yh3, g0b, g1a, llA);
    // Level 2: llA (fp16) + yh2 -> llB (fp16). TI=64 -> grid.x = 4.
    j2_fused<64, 64, _Float16, _Float16><<<dim3(4, NC), 256, 0, stream>>>(
        llA, yh2, g0b, g1a, llB);
    // Level 1: llB (fp16) + yh1 -> out (fp32). TI=32 -> grid.x = 8.
    j1_fused<128, 128, _Float16><<<dim3(8, NC), 256, 0, stream>>>(
        llB, yh1, g0o, g1o, out);
}

// Round 8
// 100.294 us; speedup vs baseline: 1.1816x; 1.1816x over previous
//
#include <hip/hip_runtime.h>

#define SC 0.70710678118654752440f

typedef _Float16 h4v __attribute__((ext_vector_type(4)));
typedef _Float16 h8v __attribute__((ext_vector_type(8)));

__device__ __forceinline__ float4 ld4(const float* __restrict__ p) {
    return *(const float4*)p;
}
__device__ __forceinline__ float4 ld4(const _Float16* __restrict__ p) {
    h4v h = *(const h4v*)p;
    return make_float4((float)h[0], (float)h[1], (float)h[2], (float)h[3]);
}
__device__ __forceinline__ void st4(float* __restrict__ p, float4 v) {
    *(float4*)p = v;
}
__device__ __forceinline__ void st4(_Float16* __restrict__ p, float4 v) {
    h4v h;
    h[0] = (_Float16)v.x; h[1] = (_Float16)v.y;
    h[2] = (_Float16)v.z; h[3] = (_Float16)v.w;
    *(h4v*)p = h;
}

// pack two float4 (y1 4-slot, y2 4-slot) into one 16B fp16 chunk
__device__ __forceinline__ h8v pack8(float4 a, float4 b) {
    h8v h;
    h[0] = (_Float16)a.x; h[1] = (_Float16)a.y;
    h[2] = (_Float16)a.z; h[3] = (_Float16)a.w;
    h[4] = (_Float16)b.x; h[5] = (_Float16)b.y;
    h[6] = (_Float16)b.z; h[7] = (_Float16)b.w;
    return h;
}
// unpack chunk; rv = chunk was reflection-mapped -> full 4-slot reversal
__device__ __forceinline__ void unpack8(h8v h, bool rv, float4& y1, float4& y2) {
    float4 p = make_float4((float)h[0], (float)h[1], (float)h[2], (float)h[3]);
    float4 q = make_float4((float)h[4], (float)h[5], (float)h[6], (float)h[7]);
    float4 pr = make_float4(p.w, p.z, p.y, p.x);
    float4 qr = make_float4(q.w, q.z, q.y, q.x);
    y1 = rv ? pr : p;
    y2 = rv ? qr : q;
}

// branchless half-sample reflection in [0, n)
__device__ __forceinline__ int reflFull(int p, int n) {
    int x = max(p, ~p);
    return min(x, 2 * n - 1 - x);
}
// pair-space reflection: NP pairs; reflected pair index + swap flag
__device__ __forceinline__ int pairRefl(int t, int NP, bool& sw) {
    int x = max(t, ~t);
    int tp = min(x, 2 * NP - 1 - x);
    sw = (tp != t);
    return tp;
}

// coefficient index maps: cfl[s][k] = g0b[cflIdx], cfh[s][k] = g1a[cfhIdx]
__device__ __forceinline__ constexpr int cflIdx(int s, int k) {
    return (s == 0) ? 8 - 2 * k : (s == 1) ? 1 + 2 * k : (s == 2) ? 9 - 2 * k : 2 * k;
}
__device__ __forceinline__ constexpr int cfhIdx(int s, int k) {
    return (s == 0) ? 1 + 2 * k : (s == 1) ? 8 - 2 * k : (s == 2) ? 2 * k : 9 - 2 * k;
}

__device__ __forceinline__ float4 f4fma(float c, float4 a, float4 acc) {
    return make_float4(fmaf(c, a.x, acc.x), fmaf(c, a.y, acc.y),
                       fmaf(c, a.z, acc.z), fmaf(c, a.w, acc.w));
}
__device__ __forceinline__ float4 f4sel(bool sw, float4 a, float4 b) {
    return sw ? a : b;
}

struct Band4 { float4 e05, o05, e23, o23, e14, o14; };

// load 6 band float4s (2 complex = 4 output cols) at pair-row offset; produce
// even/odd-row-slot c2q values (unscaled by SC); sw swaps even/odd slots
__device__ __forceinline__ Band4 loadBands4(const float* __restrict__ bp, int HW2,
                                            int boff, bool sw) {
    float4 B0 = *(const float4*)(bp + 0 * HW2 + boff);
    float4 B1 = *(const float4*)(bp + 1 * HW2 + boff);
    float4 B2 = *(const float4*)(bp + 2 * HW2 + boff);
    float4 B3 = *(const float4*)(bp + 3 * HW2 + boff);
    float4 B4 = *(const float4*)(bp + 4 * HW2 + boff);
    float4 B5 = *(const float4*)(bp + 5 * HW2 + boff);
    float4 ve05 = {B0.x + B5.x, B0.y + B5.y, B0.z + B5.z, B0.w + B5.w};
    float4 vo05 = {B0.y - B5.y, B5.x - B0.x, B0.w - B5.w, B5.z - B0.z};
    float4 ve23 = {B2.x + B3.x, B2.y + B3.y, B2.z + B3.z, B2.w + B3.w};
    float4 vo23 = {B2.y - B3.y, B3.x - B2.x, B2.w - B3.w, B3.z - B2.z};
    float4 ve14 = {B1.x + B4.x, B1.y + B4.y, B1.z + B4.z, B1.w + B4.w};
    float4 vo14 = {B1.y - B4.y, B4.x - B1.x, B1.w - B4.w, B4.z - B1.z};
    Band4 r;
    r.e05 = f4sel(sw, vo05, ve05);  r.o05 = f4sel(sw, ve05, vo05);
    r.e23 = f4sel(sw, vo23, ve23);  r.o23 = f4sel(sw, ve23, vo23);
    r.e14 = f4sel(sw, vo14, ve14);  r.o14 = f4sel(sw, ve14, vo14);
    return r;
}

template <int N> struct Log2 { static constexpr int v = 1 + Log2<N / 2>::v; };
template <> struct Log2<1> { static constexpr int v = 0; };

// ---------------------------------------------------------------------------
// Fused j2 level: ll (nc,2H,2W) + yh (nc,6,H,W,2) -> out (nc,4H,4W)
// Col stage (round-6 proven): 256 tasks (qq,u4), 4 rows x 4 cols -> one h8v
// chunk per row, lane-stride-1 writes. Row stage: 8 cols per task, 3 aligned
// chunk reads at lane-stride-1 (conflict-free).
// ---------------------------------------------------------------------------
template <int H, int W, typename TIn, typename TOut>
__global__ __launch_bounds__(256) void j2_fused(
        const TIn* __restrict__ ll, const float* __restrict__ yh,
        const float* __restrict__ g0b, const float* __restrict__ g1a,
        TOut* __restrict__ out) {
    constexpr int LOGW = Log2<W>::v;
    constexpr int U4 = W / 2, LOGU4 = LOGW - 1;
    constexpr int QI = 256 / U4;         // quad-rows per tile
    constexpr int TI = 4 * QI;           // tile rows
    constexpr int r = 2 * H, COUT = 4 * W, LOGC2 = LOGW + 1;
    constexpr int HW2 = H * W * 2;
    constexpr int NCH = W / 2;           // chunks per row
    __shared__ h8v sY[TI][NCH + 1];      // +1 pad breaks cross-row write conflicts

    const int tid = threadIdx.x;
    const int nc = blockIdx.y;
    const int q0 = blockIdx.x * QI;
    const TIn* llp = ll + (size_t)nc * r * (2 * W);
    const float* bp  = yh + (size_t)nc * 6 * HW2;

    float G0[10], G1[10];
#pragma unroll
    for (int i = 0; i < 10; ++i) { G0[i] = g0b[i]; G1[i] = g1a[i]; }

    // ---- col stage
    {
        int u4 = tid & (U4 - 1);
        int qq = tid >> LOGU4;
        int q = q0 + qq;
        float4 A1[4], A1b[4], A2[4];
#pragma unroll
        for (int s = 0; s < 4; ++s) {
            A1[s] = {0, 0, 0, 0}; A1b[s] = {0, 0, 0, 0}; A2[s] = {0, 0, 0, 0};
        }
#pragma unroll
        for (int k = 0; k < 5; ++k) {
            int t = q + k - 2;
            int pe = reflFull(2 * t, r);
            int po = reflFull(2 * t + 1, r);
            float4 lle = ld4(llp + ((pe << LOGC2) + 4 * u4));
            float4 llo = ld4(llp + ((po << LOGC2) + 4 * u4));
            bool sw; int tp = pairRefl(t, H, sw);
            Band4 B = loadBands4(bp, HW2, (tp << (LOGW + 1)) + 4 * u4, sw);
#pragma unroll
            for (int s = 0; s < 4; ++s) {
                float4 lv  = (s & 1) ? llo   : lle;
                float4 v05 = (s & 1) ? B.e05 : B.o05;
                float4 v23 = (s & 1) ? B.o23 : B.e23;
                float4 v14 = (s & 1) ? B.e14 : B.o14;
                float c0 = G0[cflIdx(s, k)];
                float c1 = G1[cfhIdx(s, k)];
                A1[s]  = f4fma(c0, lv,  A1[s]);
                A1b[s] = f4fma(c1, v05, A1b[s]);
                A2[s]  = f4fma(c0, v23, f4fma(c1, v14, A2[s]));
            }
        }
#pragma unroll
        for (int s = 0; s < 4; ++s) {
            float4 w1 = f4fma(SC, A1b[s], A1[s]);
            float4 w2 = {SC * A2[s].x, SC * A2[s].y, SC * A2[s].z, SC * A2[s].w};
            sY[4 * qq + s][u4] = pack8(w1, w2);
        }
    }
    __syncthreads();

    // ---- row stage: 8 cols (2 quads) per task; 3 chunk reads
    TOut* op = out + (size_t)nc * (4 * H) * COUT;
#pragma unroll
    for (int v = 0; v < (TI * W) / 512; ++v) {
        int lin = v * 256 + tid;
        int uc = lin & (U4 - 1);
        int il = lin >> LOGU4;
        float e1[6], o1[6], e2[6], o2[6];
#pragma unroll
        for (int d = 0; d < 3; ++d) {
            int a = uc - 1 + d;
            int ac = reflFull(a, NCH);
            bool rv = (ac != a);
            float4 y1, y2;
            unpack8(sY[il][ac], rv, y1, y2);
            e1[2 * d] = y1.x;  o1[2 * d] = y1.y;
            e1[2 * d + 1] = y1.z;  o1[2 * d + 1] = y1.w;
            e2[2 * d] = y2.x;  o2[2 * d] = y2.y;
            e2[2 * d + 1] = y2.z;  o2[2 * d + 1] = y2.w;
        }
        float acc[8];
#pragma unroll
        for (int b = 0; b < 2; ++b)
#pragma unroll
            for (int s = 0; s < 4; ++s) {
                float a = 0.f;
#pragma unroll
                for (int k = 0; k < 5; ++k) {
                    int m = b + k;
                    float v1 = (s & 1) ? o1[m] : e1[m];
                    float v2 = (s & 1) ? e2[m] : o2[m];
                    a = fmaf(G0[cflIdx(s, k)], v1, a);
                    a = fmaf(G1[cfhIdx(s, k)], v2, a);
                }
                acc[4 * b + s] = a;
            }
        int grow = 4 * q0 + il;
        st4(op + (size_t)grow * COUT + 8 * uc,
            make_float4(acc[0], acc[1], acc[2], acc[3]));
        st4(op + (size_t)grow * COUT + 8 * uc + 4,
            make_float4(acc[4], acc[5], acc[6], acc[7]));
    }
}

// ---------------------------------------------------------------------------
// Fused j1: ll (nc,r,c) + yh (nc,6,H,W,2) -> out (nc,r,c), r=2H, c=2W
// Col stage (round-6 proven): 4 rows x 4 cols per thread. Row stage: 8 cols
// per task, 4 aligned chunk reads.
// ---------------------------------------------------------------------------
template <int H, int W, typename TIn>
__global__ __launch_bounds__(256) void j1_fused(
        const TIn* __restrict__ ll, const float* __restrict__ yh,
        const float* __restrict__ g0o, const float* __restrict__ g1o,
        float* __restrict__ out) {
    constexpr int LOGW = Log2<W>::v;
    constexpr int U4 = W / 2, LOGU4 = LOGW - 1;
    constexpr int QI = 256 / U4;         // quad-row groups per tile
    constexpr int TI = 4 * QI;           // tile rows
    constexpr int r = 2 * H, c = 2 * W, LOGC2 = LOGW + 1;
    constexpr int HW2 = H * W * 2;
    constexpr int NCH = W / 2;
    __shared__ h8v sY[TI][NCH + 1];

    const int tid = threadIdx.x;
    const int nc = blockIdx.y;
    const int qi0 = blockIdx.x * QI;
    const TIn* llp = ll + (size_t)nc * r * c;
    const float* bp  = yh + (size_t)nc * 6 * HW2;

    float g0f[7], g1f[5];
#pragma unroll
    for (int k = 0; k < 7; ++k) g0f[k] = g0o[6 - k];
#pragma unroll
    for (int k = 0; k < 5; ++k) g1f[k] = g1o[4 - k];

    // ---- col stage
    {
        int u4 = tid & (U4 - 1);
        int qq = tid >> LOGU4;
        int qi = qi0 + qq;
        float4 A1[4], A1b[4], A2[4];
#pragma unroll
        for (int s = 0; s < 4; ++s) {
            A1[s] = {0, 0, 0, 0}; A1b[s] = {0, 0, 0, 0}; A2[s] = {0, 0, 0, 0};
        }
        // ll contribution (g0, rows 4qi-3 .. 4qi+6)
#pragma unroll
        for (int rr = 0; rr < 10; ++rr) {
            int p = reflFull(4 * qi - 3 + rr, r);
            float4 v = ld4(llp + ((p << LOGC2) + 4 * u4));
#pragma unroll
            for (int di = 0; di < 4; ++di) {
                int k = rr - di;
                if (k >= 0 && k <= 6) A1[di] = f4fma(g0f[k], v, A1[di]);
            }
        }
        // band contributions (pair rows 2qi-2 .. 2qi+3)
#pragma unroll
        for (int tr = 0; tr < 6; ++tr) {
            int t = 2 * qi - 2 + tr;
            bool sw; int tp = pairRefl(t, H, sw);
            Band4 B = loadBands4(bp, HW2, (tp << (LOGW + 1)) + 4 * u4, sw);
#pragma unroll
            for (int di = 0; di < 4; ++di) {
                int k1e = 2 * tr - di - 2;
                int k1o = k1e + 1;
                int k0e = 2 * tr - di - 1;
                int k0o = k0e + 1;
                if (k1e >= 0 && k1e <= 4) {
                    A1b[di] = f4fma(g1f[k1e], B.e05, A1b[di]);
                    A2[di]  = f4fma(g1f[k1e], B.e14, A2[di]);
                }
                if (k1o >= 0 && k1o <= 4) {
                    A1b[di] = f4fma(g1f[k1o], B.o05, A1b[di]);
                    A2[di]  = f4fma(g1f[k1o], B.o14, A2[di]);
                }
                if (k0e >= 0 && k0e <= 6) A2[di] = f4fma(g0f[k0e], B.e23, A2[di]);
                if (k0o >= 0 && k0o <= 6) A2[di] = f4fma(g0f[k0o], B.o23, A2[di]);
            }
        }
#pragma unroll
        for (int di = 0; di < 4; ++di) {
            float4 w1 = f4fma(SC, A1b[di], A1[di]);
            float4 w2 = {SC * A2[di].x, SC * A2[di].y, SC * A2[di].z, SC * A2[di].w};
            sY[4 * qq + di][u4] = pack8(w1, w2);
        }
    }
    __syncthreads();

    // ---- row stage: 8 cols per task; 4 chunk reads
    float* op = out + (size_t)nc * r * c;
#pragma unroll
    for (int v = 0; v < (TI * W) / 1024; ++v) {
        int lin = v * 256 + tid;
        int g8 = lin & (W / 4 - 1);     // 8-col group
        int il = lin >> (LOGW - 2);
        float e1[8], o1[8], e2[8], o2[8];
#pragma unroll
        for (int d = 0; d < 4; ++d) {
            int a = 2 * g8 - 1 + d;
            int ac = reflFull(a, NCH);
            bool rv = (ac != a);
            float4 y1, y2;
            unpack8(sY[il][ac], rv, y1, y2);
            e1[2 * d] = y1.x;  o1[2 * d] = y1.y;
            e1[2 * d + 1] = y1.z;  o1[2 * d + 1] = y1.w;
            e2[2 * d] = y2.x;  o2[2 * d] = y2.y;
            e2[2 * d + 1] = y2.z;  o2[2 * d + 1] = y2.w;
        }
        float acc[8];
#pragma unroll
        for (int b = 0; b < 2; ++b)
#pragma unroll
            for (int s = 0; s < 4; ++s) {
                float a = 0.f;
#pragma unroll
                for (int k = 0; k < 7; ++k) {
                    int rel = s + k + 1;
                    int mm = (rel >> 1) + 2 * b;
                    a = fmaf(g0f[k], (rel & 1) ? o1[mm] : e1[mm], a);
                }
#pragma unroll
                for (int k = 0; k < 5; ++k) {
                    int rel = s + k + 2;
                    int mm = (rel >> 1) + 2 * b;
                    a = fmaf(g1f[k], (rel & 1) ? o2[mm] : e2[mm], a);
                }
                acc[4 * b + s] = a;
            }
        int grow = 4 * qi0 + il;
        *(float4*)(op + (size_t)grow * c + 8 * g8) =
            make_float4(acc[0], acc[1], acc[2], acc[3]);
        *(float4*)(op + (size_t)grow * c + 8 * g8 + 4) =
            make_float4(acc[4], acc[5], acc[6], acc[7]);
    }
}

extern "C" void kernel_launch(void* const* d_in, const int* in_sizes, int n_in,
                              void* d_out, int out_size, void* d_ws, size_t ws_size,
                              hipStream_t stream) {
    const float* yl  = (const float*)d_in[0];
    const float* yh1 = (const float*)d_in[1];
    const float* yh2 = (const float*)d_in[2];
    const float* yh3 = (const float*)d_in[3];
    const float* g0o = (const float*)d_in[4];
    const float* g1o = (const float*)d_in[5];
    const float* g0b = (const float*)d_in[7];
    const float* g1a = (const float*)d_in[8];
    float* out = (float*)d_out;

    const int NC = 256;
    char* ws = (char*)d_ws;
    _Float16* llA = (_Float16*)ws;                        // (NC,128,128) fp16, 8MB
    _Float16* llB = (_Float16*)(ws + ((size_t)16 << 20)); // (NC,256,256) fp16, 32MB

    // Level 3: yl (fp32) + yh3 -> llA (fp16). TI=64 -> grid.x = 128/64 = 2.
    j2_fused<32, 32, float, _Float16><<<dim3(2, NC), 256, 0, stream>>>(
        yl, yh3, g0b, g1a, llA);
    // Level 2: llA (fp16) + yh2 -> llB (fp16). TI=32 -> grid.x = 256/32 = 8.
    j2_fused<64, 64, _Float16, _Float16><<<dim3(8, NC), 256, 0, stream>>>(
        llA, yh2, g0b, g1a, llB);
    // Level 1: llB (fp16) + yh1 -> out (fp32). TI=16 -> grid.x = 256/16 = 16.
    j1_fused<128, 128, _Float16><<<dim3(16, NC), 256, 0, stream>>>(
        llB, yh1, g0o, g1o, out);
}